// Round 16
// baseline (145.076 us; speedup 1.0000x reference)
//
#include <hip/hip_runtime.h>
#include <hip/hip_fp16.h>

typedef _Float16 f16x8 __attribute__((ext_vector_type(8)));
typedef _Float16 f16x4 __attribute__((ext_vector_type(4)));
typedef float f32x4 __attribute__((ext_vector_type(4)));

// ---------- fused weight transpose f32 -> f16: WT[n][k] = W[k][n]*scale ----------
__global__ __launch_bounds__(256) void wtrans6_kernel(
    const float* __restrict__ Wq, const float* __restrict__ Wk,
    const float* __restrict__ Wq2, const float* __restrict__ Wk2,
    const float* __restrict__ Wv, const float* __restrict__ Wo,
    __half* __restrict__ WqcT, __half* __restrict__ WkcT,
    __half* __restrict__ WvT, __half* __restrict__ WoT) {
  const float* src;
  __half* dst;
  float scale = 1.0f;
  switch (blockIdx.z) {
    case 0: src = Wq;  dst = WqcT;              scale = 0.125f; break;
    case 1: src = Wq2; dst = WqcT + 512 * 512;  break;
    case 2: src = Wk;  dst = WkcT;              break;
    case 3: src = Wk2; dst = WkcT + 512 * 512;  break;
    case 4: src = Wv;  dst = WvT;               break;
    default: src = Wo; dst = WoT;               break;
  }
  __shared__ float t[32][33];
  int n0 = blockIdx.x * 32, k0 = blockIdx.y * 32;
  int tx = threadIdx.x, ty = threadIdx.y;  // (32,8)
#pragma unroll
  for (int i = 0; i < 4; i++)
    t[ty + i * 8][tx] = src[(size_t)(k0 + ty + i * 8) * 512 + n0 + tx];
  __syncthreads();
#pragma unroll
  for (int i = 0; i < 4; i++)
    dst[(size_t)(n0 + ty + i * 8) * 512 + k0 + tx] = __float2half(t[tx][ty + i * 8] * scale);
}

// ---------- mask pack body (uint4 layout): 2-bit code = am+bm ----------
// packed[bk][lane][mi] : uint4 (word=kt>>2, bit=(kt&3)*8 + r*2), bk=((b*32+qt)*4+w)
__device__ __forceinline__ void maskprep_body(const int* __restrict__ am,
                                              const int* __restrict__ bm,
                                              uint32_t* __restrict__ packed, int bk,
                                              int t) {
  int w = bk & 3, bqt = bk >> 2, qt = bqt & 31, b = bqt >> 5;
  int mi = t >> 6, lane = t & 63;
  int lg = lane >> 4, l15 = lane & 15;
  int qbase = qt * 32 + mi * 16 + lg * 4;
  int kbase = w * 256 + l15;
  uint32_t outw[4] = {0u, 0u, 0u, 0u};
#pragma unroll
  for (int kt = 0; kt < 16; kt++) {
    int k = kbase + kt * 16;
#pragma unroll
    for (int r = 0; r < 4; r++) {
      size_t idx = ((size_t)(b * 1024 + qbase + r)) * 1024 + k;
      uint32_t code = (am[idx] ? 1u : 0u) + (bm[idx] ? 1u : 0u);
      outw[kt >> 2] |= code << (((kt & 3) << 3) + (r << 1));
    }
  }
  uint4* dst = (uint4*)packed + ((size_t)bk * 64 + lane) * 2 + mi;
  *dst = make_uint4(outw[0], outw[1], outw[2], outw[3]);
}

// ---------- shared GEMM body ----------
// MODE 0: C row-major (full 256B-segment stores).
// MODE 2: K fragment-pack  Kpk[bh][kblk16][ks(4)][lane(64)][8]
// MODE 1: V fragment-pack  Vpk[bh][k32][dvblk(4)][lane(64)][8]
template <int AF32, int MODE>
__device__ __forceinline__ void gemm_body(const void* Ap, const __half* Bt, __half* C,
                                          int N, int bx, int by,
                                          __half* __restrict__ pk) {
  __shared__ __align__(16) _Float16 smem[10240];  // As 128x40 | Bs 128x40 (20 KB)
  _Float16(*As)[40] = (_Float16(*)[40])smem;
  _Float16(*Bs)[40] = (_Float16(*)[40])(smem + 5120);
  int tid = threadIdx.x;
  int wave = tid >> 6, lane = tid & 63;
  int lg = lane >> 4, l15 = lane & 15;
  int wm = (wave >> 1) * 64, wn = (wave & 1) * 64;
  int bm0 = by * 128, bn0 = bx * 128;
  int srow = tid >> 1, sseg = (tid & 1) * 16;
  const float* Af = (const float*)Ap;
  const __half* Ah = (const __half*)Ap;
  f32x4 acc[4][4];
#pragma unroll
  for (int i = 0; i < 4; i++)
#pragma unroll
    for (int j = 0; j < 4; j++) acc[i][j] = (f32x4){0.f, 0.f, 0.f, 0.f};

  for (int kt = 0; kt < 16; kt++) {
    int k0 = kt * 32;
    if (AF32) {
      const float* s = Af + (size_t)(bm0 + srow) * 512 + k0 + sseg;
      _Float16* d = &As[srow][sseg];
#pragma unroll
      for (int i = 0; i < 16; i += 4) {
        float4 v = *(const float4*)(s + i);
        d[i] = (_Float16)v.x; d[i + 1] = (_Float16)v.y;
        d[i + 2] = (_Float16)v.z; d[i + 3] = (_Float16)v.w;
      }
    } else {
      const __half* s = Ah + (size_t)(bm0 + srow) * 512 + k0 + sseg;
      *(uint4*)&As[srow][sseg] = *(const uint4*)s;
      *(uint4*)(&As[srow][sseg] + 8) = *(const uint4*)(s + 8);
    }
    {
      const __half* s = Bt + (size_t)(bn0 + srow) * 512 + k0 + sseg;
      *(uint4*)&Bs[srow][sseg] = *(const uint4*)s;
      *(uint4*)(&Bs[srow][sseg] + 8) = *(const uint4*)(s + 8);
    }
    __syncthreads();
    f16x8 af[4], bf[4];
#pragma unroll
    for (int i = 0; i < 4; i++) af[i] = *(const f16x8*)&As[wm + i * 16 + l15][lg * 8];
#pragma unroll
    for (int j = 0; j < 4; j++) bf[j] = *(const f16x8*)&Bs[wn + j * 16 + l15][lg * 8];
#pragma unroll
    for (int i = 0; i < 4; i++)
#pragma unroll
      for (int j = 0; j < 4; j++)
        acc[i][j] = __builtin_amdgcn_mfma_f32_16x16x32_f16(af[i], bf[j], acc[i][j], 0, 0, 0);
    __syncthreads();
  }

  // ---- LDS-staged epilogue: two passes of 64 rows; cb stride 136 (16B-aligned) ----
  _Float16* cb = smem;  // 64*136 = 8704 halves
#pragma unroll
  for (int ph = 0; ph < 2; ph++) {
    __syncthreads();
    if ((wave >> 1) == ph) {
#pragma unroll
      for (int i = 0; i < 4; i++)
#pragma unroll
        for (int j = 0; j < 4; j++)
#pragma unroll
          for (int r = 0; r < 4; r++)
            cb[(i * 16 + lg * 4 + r) * 136 + wn + j * 16 + l15] =
                (_Float16)acc[i][j][r];
    }
    __syncthreads();
    if (MODE == 0) {
#pragma unroll
      for (int rr = 0; rr < 4; rr++) {
        int row = rr * 16 + (tid >> 4);   // 0..63
        int colh = (tid & 15) * 8;        // 16 lanes cover 256B contiguous
        uint4 v = *(const uint4*)&cb[row * 136 + colh];
        *(uint4*)&C[(size_t)(bm0 + ph * 64 + row) * N + bn0 + colh] = v;
      }
    } else if (MODE == 2) {
      // K fragment pack: tile cols = [K(512)|K2(512)], bx<4 -> K (ks 0,1), else K2 (ks 2,3)
      int m0 = bm0 + ph * 64;
      int b = m0 >> 10;
      int kblk0 = (m0 & 1023) >> 4;
      int isK2 = (bn0 >= 512) ? 1 : 0;
      int hpair = (isK2 ? (bx - 4) : bx) * 2;
      int sel = tid >> 6;          // 0..3
      int hh = sel >> 1, ksl = sel & 1;
      int bh = b * 8 + hpair + hh;
      int ksd = isK2 * 2 + ksl;
#pragma unroll
      for (int kb = 0; kb < 4; kb++) {
        f16x8 v = *(const f16x8*)&cb[(kb * 16 + l15) * 136 + hh * 64 + ksl * 32 + lg * 8];
        *(f16x8*)(pk + ((((size_t)bh * 64 + kblk0 + kb) * 4 + ksd) * 64 + lane) * 8) = v;
      }
    } else {
      // V fragment pack: lane's 8 halves = 8 consecutive KEYS for fixed dv (LDS transpose)
      int m0 = bm0 + ph * 64;
      int b = m0 >> 10;
      int k320 = (m0 & 1023) >> 5;
      int sel = tid >> 6;
      int hh = sel >> 1, kk2 = sel & 1;
      int bh = b * 8 + bx * 2 + hh;
#pragma unroll
      for (int dvb = 0; dvb < 4; dvb++) {
        f16x8 v;
#pragma unroll
        for (int j = 0; j < 8; j++)
          v[j] = cb[(kk2 * 32 + lg * 8 + j) * 136 + hh * 64 + dvb * 16 + l15];
        *(f16x8*)(pk + ((((size_t)bh * 32 + k320 + kk2) * 4 + dvb) * 64 + lane) * 8) = v;
      }
    }
  }
}

// fused Q/K/V projections + fragment packing + mask pack (z selects)
__global__ __launch_bounds__(256) void proj_kernel(
    const float* __restrict__ inQ, const float* __restrict__ inK,
    const float* __restrict__ inV, const __half* __restrict__ WqcT,
    const __half* __restrict__ WkcT, const __half* __restrict__ WvT,
    const int* __restrict__ am, const int* __restrict__ bm,
    __half* __restrict__ QQ2, __half* __restrict__ Kpk, __half* __restrict__ Vpk,
    uint32_t* __restrict__ packed) {
  int z = blockIdx.z;
  if (z == 0) {
    gemm_body<1, 0>(inQ, WqcT, QQ2, 1024, blockIdx.x, blockIdx.y, nullptr);
  } else if (z == 1) {
    gemm_body<1, 2>(inK, WkcT, nullptr, 1024, blockIdx.x, blockIdx.y, Kpk);
  } else if (z == 2) {
    if (blockIdx.x >= 4) return;
    gemm_body<1, 1>(inV, WvT, nullptr, 512, blockIdx.x, blockIdx.y, Vpk);
  } else {
    // mask pack: 256 blocks x 256 threads cover bk 0..511 (2 per block)
    int bk = (blockIdx.y * 8 + blockIdx.x) * 2 + (threadIdx.x >> 7);
    maskprep_body(am, bm, packed, bk, threadIdx.x & 127);
  }
}

// ---------- fused attention (round-11 configuration, UNCHANGED — best measured) ----------
// INVARIANTS (round-7 isolation): 2D grid (qt,bh), no swizzle; attn global writes
// from registers, scalar f32 (NO nt — round-15 showed nt costs +15us), ONE phase
// before PV; 67.6 KB LDS -> 2 blocks/CU; coalesced Kpk/Vpk fragment loads.
__global__ __launch_bounds__(256, 2) void attn_kernel(
    const __half* __restrict__ QQ2, const __half* __restrict__ Kpk,
    const __half* __restrict__ Vpk, const uint32_t* __restrict__ packed,
    float* __restrict__ attn_out, __half* __restrict__ CTX) {
  int qt = blockIdx.x, bh = blockIdx.y;
  int b = bh >> 3, h = bh & 7;
  int q0 = qt * 32;
  int tid = threadIdx.x;
  int wave = tid >> 6, lane = tid & 63;
  int lg = lane >> 4, l15 = lane & 15;
  int kw = wave * 256;

  __shared__ __align__(16) _Float16 P[4][32][264];  // 67.6 KB -> 2 blocks/CU
  __shared__ float redmax[4][32], redsum[4][32];

  // ---- Q fragments: concat(Q/8, Q2), 128 dims ----
  f16x8 qf[2][4];
  const __half* Qb = QQ2 + ((size_t)(b * 1024 + q0)) * 1024 + h * 64;
#pragma unroll
  for (int mi = 0; mi < 2; mi++)
#pragma unroll
    for (int ks = 0; ks < 4; ks++) {
      int off = (ks < 2) ? ks * 32 : 512 + (ks - 2) * 32;
      qf[mi][ks] = *(const f16x8*)(Qb + (size_t)(mi * 16 + l15) * 1024 + off + lg * 8);
    }

  // ---- packed mask words ----
  uint4 mw[2];
  {
    const uint4* mp =
        (const uint4*)packed + ((size_t)((b * 32 + qt) * 4 + wave) * 64 + lane) * 2;
    mw[0] = mp[0];
    mw[1] = mp[1];
  }

  // ---- phase 1: scores -> f16 regs, track max (coalesced Kpk loads) ----
  f16x4 sc16[2][16];
  float mx[2][4];
#pragma unroll
  for (int mi = 0; mi < 2; mi++)
#pragma unroll
    for (int r = 0; r < 4; r++) mx[mi][r] = -3.0e38f;
  const __half* Kbp = Kpk + ((size_t)bh * 64 + wave * 16) * 4 * 512 + lane * 8;
#pragma unroll
  for (int kt = 0; kt < 16; kt++) {
    const __half* kp = Kbp + (size_t)kt * 4 * 512;
    f16x8 kf[4];
    kf[0] = *(const f16x8*)kp;
    kf[1] = *(const f16x8*)(kp + 512);
    kf[2] = *(const f16x8*)(kp + 1024);
    kf[3] = *(const f16x8*)(kp + 1536);
#pragma unroll
    for (int mi = 0; mi < 2; mi++) {
      f32x4 s = (f32x4){0.f, 0.f, 0.f, 0.f};
#pragma unroll
      for (int ks = 0; ks < 4; ks++)
        s = __builtin_amdgcn_mfma_f32_16x16x32_f16(qf[mi][ks], kf[ks], s, 0, 0, 0);
      uint32_t mword = ((const uint32_t*)&mw[mi])[kt >> 2];
      f16x4 sv;
#pragma unroll
      for (int r = 0; r < 4; r++) {
        uint32_t code = (mword >> (((kt & 3) << 3) + (r << 1))) & 3u;
        float sval = s[r] - 30000.0f * (float)code;
        sv[r] = (_Float16)sval;
        mx[mi][r] = fmaxf(mx[mi][r], (float)sv[r]);
      }
      sc16[mi][kt] = sv;
    }
  }

  // ---- max reduce ----
#pragma unroll
  for (int mi = 0; mi < 2; mi++)
#pragma unroll
    for (int r = 0; r < 4; r++) {
      float m = mx[mi][r];
#pragma unroll
      for (int o = 1; o < 16; o <<= 1) m = fmaxf(m, __shfl_xor(m, o));
      if (l15 == 0) redmax[wave][mi * 16 + lg * 4 + r] = m;
    }
  __syncthreads();
  float mfin[2][4];
#pragma unroll
  for (int mi = 0; mi < 2; mi++)
#pragma unroll
    for (int r = 0; r < 4; r++) {
      int row = mi * 16 + lg * 4 + r;
      mfin[mi][r] = fmaxf(fmaxf(redmax[0][row], redmax[1][row]),
                          fmaxf(redmax[2][row], redmax[3][row]));
    }

  // ---- p = exp(s-m) in f16 regs, sum reduce ----
  float sm[2][4];
#pragma unroll
  for (int mi = 0; mi < 2; mi++)
#pragma unroll
    for (int r = 0; r < 4; r++) sm[mi][r] = 0.f;
#pragma unroll
  for (int kt = 0; kt < 16; kt++)
#pragma unroll
    for (int mi = 0; mi < 2; mi++) {
      f16x4 sv = sc16[mi][kt];
      f16x4 pv;
#pragma unroll
      for (int r = 0; r < 4; r++) {
        float p = __expf((float)sv[r] - mfin[mi][r]);
        sm[mi][r] += p;
        pv[r] = (_Float16)p;
      }
      sc16[mi][kt] = pv;
    }
#pragma unroll
  for (int mi = 0; mi < 2; mi++)
#pragma unroll
    for (int r = 0; r < 4; r++) {
      float s = sm[mi][r];
#pragma unroll
      for (int o = 1; o < 16; o <<= 1) s += __shfl_xor(s, o);
      if (l15 == 0) redsum[wave][mi * 16 + lg * 4 + r] = s;
    }
  __syncthreads();
  float inv[2][4];
#pragma unroll
  for (int mi = 0; mi < 2; mi++)
#pragma unroll
    for (int r = 0; r < 4; r++) {
      int row = mi * 16 + lg * 4 + r;
      inv[mi][r] =
          1.0f / (redsum[0][row] + redsum[1][row] + redsum[2][row] + redsum[3][row]);
    }

  // ---- write phase: attn strip from regs (plain scalar f32) + stage P[wave] ----
  float* ab = attn_out + ((size_t)bh * 1024 + q0) * 1024;
#pragma unroll
  for (int mi = 0; mi < 2; mi++)
#pragma unroll
    for (int kt = 0; kt < 16; kt++)
#pragma unroll
      for (int r = 0; r < 4; r++) {
        int row = mi * 16 + lg * 4 + r;
        int col = kw + kt * 16 + l15;
        float a = (float)sc16[mi][kt][r] * inv[mi][r];
        ab[(size_t)row * 1024 + col] = a;
        P[wave][row][kt * 16 + l15] = (_Float16)a;
      }
  __syncthreads();

  // ---- PV over 4 chunks, no further barriers; wave owns dv slice [16w,16w+16) ----
  f32x4 ctx[2];
  ctx[0] = (f32x4){0.f, 0.f, 0.f, 0.f};
  ctx[1] = (f32x4){0.f, 0.f, 0.f, 0.f};
  const __half* Vbp = Vpk + ((size_t)bh * 32 * 4 + wave) * 512 + lane * 8;
#pragma unroll
  for (int c = 0; c < 4; c++) {
#pragma unroll
    for (int kk = 0; kk < 8; kk++) {
      int k32 = c * 8 + kk;
      f16x8 pa0 = *(const f16x8*)&P[c][l15][kk * 32 + lg * 8];
      f16x8 pa1 = *(const f16x8*)&P[c][16 + l15][kk * 32 + lg * 8];
      f16x8 vf = *(const f16x8*)(Vbp + (size_t)k32 * 4 * 512);
      ctx[0] = __builtin_amdgcn_mfma_f32_16x16x32_f16(pa0, vf, ctx[0], 0, 0, 0);
      ctx[1] = __builtin_amdgcn_mfma_f32_16x16x32_f16(pa1, vf, ctx[1], 0, 0, 0);
    }
  }

  // ---- ctx write: wave owns dv slice [16w,16w+16) ----
#pragma unroll
  for (int mi = 0; mi < 2; mi++)
#pragma unroll
    for (int r = 0; r < 4; r++) {
      int row = mi * 16 + lg * 4 + r;
      CTX[(size_t)(b * 1024 + q0 + row) * 512 + h * 64 + wave * 16 + l15] =
          __float2half(ctx[mi][r]);
    }
}

// ---------- fused Wo-GEMM + residual + LayerNorm ----------
// 64 blocks x 512 threads (8 waves). Block computes 64 full rows x 512 cols of
// O = CTX @ WoT^T, stages the tile in LDS, then wave-per-row LN (8 rows/wave).
__global__ __launch_bounds__(512) void woln_kernel(
    const __half* __restrict__ CTX, const __half* __restrict__ WoT,
    const float* __restrict__ resid, const float* __restrict__ g,
    const float* __restrict__ bb, float* __restrict__ out) {
  __shared__ __align__(16) char smemraw[66560];
  _Float16(*As)[40] = (_Float16(*)[40])smemraw;             // 64x40 (5.1 KB)
  _Float16(*Bs)[40] = (_Float16(*)[40])(smemraw + 5120);    // 512x40 (41 KB)
  int tid = threadIdx.x;
  int wave = tid >> 6, lane = tid & 63;
  int lg = lane >> 4, l15 = lane & 15;
  int bm0 = blockIdx.x * 64;
  int wn = wave * 64;
  f32x4 acc[4][4];
#pragma unroll
  for (int i = 0; i < 4; i++)
#pragma unroll
    for (int j = 0; j < 4; j++) acc[i][j] = (f32x4){0.f, 0.f, 0.f, 0.f};

  for (int kt = 0; kt < 16; kt++) {
    int k0 = kt * 32;
    {  // As: 64 rows x 32 k (8B per thread)
      int row = tid >> 3, off = (tid & 7) * 4;
      *(uint2*)&As[row][off] =
          *(const uint2*)(CTX + (size_t)(bm0 + row) * 512 + k0 + off);
    }
    {  // Bs: 512 n-rows x 32 k (64B per thread)
      const __half* s = WoT + (size_t)tid * 512 + k0;
      *(uint4*)&Bs[tid][0] = *(const uint4*)s;
      *(uint4*)&Bs[tid][8] = *(const uint4*)(s + 8);
      *(uint4*)&Bs[tid][16] = *(const uint4*)(s + 16);
      *(uint4*)&Bs[tid][24] = *(const uint4*)(s + 24);
    }
    __syncthreads();
    f16x8 af[4], bf[4];
#pragma unroll
    for (int i = 0; i < 4; i++) af[i] = *(const f16x8*)&As[i * 16 + l15][lg * 8];
#pragma unroll
    for (int j = 0; j < 4; j++) bf[j] = *(const f16x8*)&Bs[wn + j * 16 + l15][lg * 8];
#pragma unroll
    for (int i = 0; i < 4; i++)
#pragma unroll
      for (int j = 0; j < 4; j++)
        acc[i][j] = __builtin_amdgcn_mfma_f32_16x16x32_f16(af[i], bf[j], acc[i][j], 0, 0, 0);
    __syncthreads();
  }

  // stage O tile: cb[64][520] f16 (66.6 KB, reuses smem)
  _Float16(*cb)[520] = (_Float16(*)[520])smemraw;
#pragma unroll
  for (int i = 0; i < 4; i++)
#pragma unroll
    for (int j = 0; j < 4; j++)
#pragma unroll
      for (int r = 0; r < 4; r++)
        cb[i * 16 + lg * 4 + r][wn + j * 16 + l15] = (_Float16)acc[i][j][r];
  __syncthreads();

  // LN: wave handles rows [8*wave, 8*wave+8); lane owns 8 cols
  float4 g0 = *(const float4*)(g + lane * 8);
  float4 g1 = *(const float4*)(g + lane * 8 + 4);
  float4 b0 = *(const float4*)(bb + lane * 8);
  float4 b1 = *(const float4*)(bb + lane * 8 + 4);
#pragma unroll
  for (int rr = 0; rr < 8; rr++) {
    int row = wave * 8 + rr;
    size_t base = (size_t)(bm0 + row) * 512 + lane * 8;
    f16x8 ov = *(const f16x8*)&cb[row][lane * 8];
    float4 r0 = *(const float4*)(resid + base);
    float4 r1 = *(const float4*)(resid + base + 4);
    float x[8];
    x[0] = (float)ov[0] + r0.x; x[1] = (float)ov[1] + r0.y;
    x[2] = (float)ov[2] + r0.z; x[3] = (float)ov[3] + r0.w;
    x[4] = (float)ov[4] + r1.x; x[5] = (float)ov[5] + r1.y;
    x[6] = (float)ov[6] + r1.z; x[7] = (float)ov[7] + r1.w;
    float s = 0.f;
#pragma unroll
    for (int i = 0; i < 8; i++) s += x[i];
#pragma unroll
    for (int o = 1; o < 64; o <<= 1) s += __shfl_xor(s, o);
    float mean = s * (1.0f / 512.0f);
    float d[8], v = 0.f;
#pragma unroll
    for (int i = 0; i < 8; i++) { d[i] = x[i] - mean; v += d[i] * d[i]; }
#pragma unroll
    for (int o = 1; o < 64; o <<= 1) v += __shfl_xor(v, o);
    float rs = rsqrtf(v * (1.0f / 512.0f) + 1e-5f);
    f32x4 o0 = {d[0] * rs * g0.x + b0.x, d[1] * rs * g0.y + b0.y,
                d[2] * rs * g0.z + b0.z, d[3] * rs * g0.w + b0.w};
    f32x4 o1 = {d[4] * rs * g1.x + b1.x, d[5] * rs * g1.y + b1.y,
                d[6] * rs * g1.z + b1.z, d[7] * rs * g1.w + b1.w};
    __builtin_nontemporal_store(o0, (f32x4*)(out + base));
    __builtin_nontemporal_store(o1, (f32x4*)(out + base + 4));
  }
}

extern "C" void kernel_launch(void* const* d_in, const int* in_sizes, int n_in,
                              void* d_out, int out_size, void* d_ws, size_t ws_size,
                              hipStream_t stream) {
  const float* inQ = (const float*)d_in[0];
  const float* inK = (const float*)d_in[1];
  const float* inV = (const float*)d_in[2];
  const int* am = (const int*)d_in[3];
  const int* bmk = (const int*)d_in[4];
  const float* Wq = (const float*)d_in[5];
  const float* Wk = (const float*)d_in[6];
  const float* Wq2 = (const float*)d_in[7];
  const float* Wk2 = (const float*)d_in[8];
  const float* Wv = (const float*)d_in[9];
  const float* Wo = (const float*)d_in[10];
  const float* lng = (const float*)d_in[11];
  const float* lnb = (const float*)d_in[12];

  char* ws = (char*)d_ws;
  __half* WqcT = (__half*)ws; ws += (size_t)1024 * 512 * 2;
  __half* WkcT = (__half*)ws; ws += (size_t)1024 * 512 * 2;
  __half* WvT = (__half*)ws;  ws += (size_t)512 * 512 * 2;
  __half* WoT = (__half*)ws;  ws += (size_t)512 * 512 * 2;
  __half* QQ2 = (__half*)ws;  ws += (size_t)4096 * 1024 * 2;
  __half* Kpk = (__half*)ws;  ws += (size_t)4096 * 1024 * 2;
  __half* Vpk = (__half*)ws;  ws += (size_t)4096 * 512 * 2;
  __half* CTX = (__half*)ws;  ws += (size_t)4096 * 512 * 2;
  uint32_t* packed = (uint32_t*)ws; ws += (size_t)512 * 64 * 2 * 16;

  float* out0 = (float*)d_out;
  float* attn_out = out0 + (size_t)4 * 1024 * 512;

  wtrans6_kernel<<<dim3(16, 16, 6), dim3(32, 8), 0, stream>>>(Wq, Wk, Wq2, Wk2, Wv, Wo,
                                                              WqcT, WkcT, WvT, WoT);
  proj_kernel<<<dim3(8, 32, 4), 256, 0, stream>>>(inQ, inK, inV, WqcT, WkcT, WvT, am,
                                                  bmk, QQ2, Kpk, Vpk, packed);
  attn_kernel<<<dim3(32, 32), 256, 0, stream>>>(QQ2, Kpk, Vpk, packed, attn_out, CTX);
  woln_kernel<<<64, 512, 0, stream>>>(CTX, WoT, inQ, lng, lnb, out0);
}

// Round 17
// 125.763 us; speedup vs baseline: 1.1536x; 1.1536x over previous
//
#include <hip/hip_runtime.h>
#include <hip/hip_fp16.h>

typedef _Float16 f16x8 __attribute__((ext_vector_type(8)));
typedef _Float16 f16x4 __attribute__((ext_vector_type(4)));
typedef float f32x4 __attribute__((ext_vector_type(4)));

// ---------- fused weight transpose f32 -> f16: WT[n][k] = W[k][n]*scale ----------
__global__ __launch_bounds__(256) void wtrans6_kernel(
    const float* __restrict__ Wq, const float* __restrict__ Wk,
    const float* __restrict__ Wq2, const float* __restrict__ Wk2,
    const float* __restrict__ Wv, const float* __restrict__ Wo,
    __half* __restrict__ WqcT, __half* __restrict__ WkcT,
    __half* __restrict__ WvT, __half* __restrict__ WoT) {
  const float* src;
  __half* dst;
  float scale = 1.0f;
  switch (blockIdx.z) {
    case 0: src = Wq;  dst = WqcT;              scale = 0.125f; break;
    case 1: src = Wq2; dst = WqcT + 512 * 512;  break;
    case 2: src = Wk;  dst = WkcT;              break;
    case 3: src = Wk2; dst = WkcT + 512 * 512;  break;
    case 4: src = Wv;  dst = WvT;               break;
    default: src = Wo; dst = WoT;               break;
  }
  __shared__ float t[32][33];
  int n0 = blockIdx.x * 32, k0 = blockIdx.y * 32;
  int tx = threadIdx.x, ty = threadIdx.y;  // (32,8)
#pragma unroll
  for (int i = 0; i < 4; i++)
    t[ty + i * 8][tx] = src[(size_t)(k0 + ty + i * 8) * 512 + n0 + tx];
  __syncthreads();
#pragma unroll
  for (int i = 0; i < 4; i++)
    dst[(size_t)(n0 + ty + i * 8) * 512 + k0 + tx] = __float2half(t[tx][ty + i * 8] * scale);
}

// ---------- mask pack body (uint4 layout): 2-bit code = am+bm ----------
// packed[bk][lane][mi] : uint4 (word=kt>>2, bit=(kt&3)*8 + r*2), bk=((b*32+qt)*4+w)
__device__ __forceinline__ void maskprep_body(const int* __restrict__ am,
                                              const int* __restrict__ bm,
                                              uint32_t* __restrict__ packed, int bk,
                                              int t) {
  int w = bk & 3, bqt = bk >> 2, qt = bqt & 31, b = bqt >> 5;
  int mi = t >> 6, lane = t & 63;
  int lg = lane >> 4, l15 = lane & 15;
  int qbase = qt * 32 + mi * 16 + lg * 4;
  int kbase = w * 256 + l15;
  uint32_t outw[4] = {0u, 0u, 0u, 0u};
#pragma unroll
  for (int kt = 0; kt < 16; kt++) {
    int k = kbase + kt * 16;
#pragma unroll
    for (int r = 0; r < 4; r++) {
      size_t idx = ((size_t)(b * 1024 + qbase + r)) * 1024 + k;
      uint32_t code = (am[idx] ? 1u : 0u) + (bm[idx] ? 1u : 0u);
      outw[kt >> 2] |= code << (((kt & 3) << 3) + (r << 1));
    }
  }
  uint4* dst = (uint4*)packed + ((size_t)bk * 64 + lane) * 2 + mi;
  *dst = make_uint4(outw[0], outw[1], outw[2], outw[3]);
}

// ---------- shared GEMM body ----------
// MODE 0: C row-major (full 256B-segment stores).
// MODE 1: V fragment-pack  Vpk[bh][k32][dvblk(4)][lane(64)][8]
// MODE 2: K fragment-pack  Kpk[bh][kblk16][ks(4)][lane(64)][8]
// MODE 3: Q fragment-pack  Qpk[bqt(128)][h(8)][mi(2)][ks(4)][lane(64)][8]
template <int AF32, int MODE>
__device__ __forceinline__ void gemm_body(const void* Ap, const __half* Bt, __half* C,
                                          int N, int bx, int by,
                                          __half* __restrict__ pk) {
  __shared__ __align__(16) _Float16 smem[10240];  // As 128x40 | Bs 128x40 (20 KB)
  _Float16(*As)[40] = (_Float16(*)[40])smem;
  _Float16(*Bs)[40] = (_Float16(*)[40])(smem + 5120);
  int tid = threadIdx.x;
  int wave = tid >> 6, lane = tid & 63;
  int lg = lane >> 4, l15 = lane & 15;
  int wm = (wave >> 1) * 64, wn = (wave & 1) * 64;
  int bm0 = by * 128, bn0 = bx * 128;
  int srow = tid >> 1, sseg = (tid & 1) * 16;
  const float* Af = (const float*)Ap;
  const __half* Ah = (const __half*)Ap;
  f32x4 acc[4][4];
#pragma unroll
  for (int i = 0; i < 4; i++)
#pragma unroll
    for (int j = 0; j < 4; j++) acc[i][j] = (f32x4){0.f, 0.f, 0.f, 0.f};

  for (int kt = 0; kt < 16; kt++) {
    int k0 = kt * 32;
    if (AF32) {
      const float* s = Af + (size_t)(bm0 + srow) * 512 + k0 + sseg;
      _Float16* d = &As[srow][sseg];
#pragma unroll
      for (int i = 0; i < 16; i += 4) {
        float4 v = *(const float4*)(s + i);
        d[i] = (_Float16)v.x; d[i + 1] = (_Float16)v.y;
        d[i + 2] = (_Float16)v.z; d[i + 3] = (_Float16)v.w;
      }
    } else {
      const __half* s = Ah + (size_t)(bm0 + srow) * 512 + k0 + sseg;
      *(uint4*)&As[srow][sseg] = *(const uint4*)s;
      *(uint4*)(&As[srow][sseg] + 8) = *(const uint4*)(s + 8);
    }
    {
      const __half* s = Bt + (size_t)(bn0 + srow) * 512 + k0 + sseg;
      *(uint4*)&Bs[srow][sseg] = *(const uint4*)s;
      *(uint4*)(&Bs[srow][sseg] + 8) = *(const uint4*)(s + 8);
    }
    __syncthreads();
    f16x8 af[4], bf[4];
#pragma unroll
    for (int i = 0; i < 4; i++) af[i] = *(const f16x8*)&As[wm + i * 16 + l15][lg * 8];
#pragma unroll
    for (int j = 0; j < 4; j++) bf[j] = *(const f16x8*)&Bs[wn + j * 16 + l15][lg * 8];
#pragma unroll
    for (int i = 0; i < 4; i++)
#pragma unroll
      for (int j = 0; j < 4; j++)
        acc[i][j] = __builtin_amdgcn_mfma_f32_16x16x32_f16(af[i], bf[j], acc[i][j], 0, 0, 0);
    __syncthreads();
  }

  // ---- LDS-staged epilogue: two passes of 64 rows; cb stride 136 (16B-aligned) ----
  _Float16* cb = smem;  // 64*136 = 8704 halves
#pragma unroll
  for (int ph = 0; ph < 2; ph++) {
    __syncthreads();
    if ((wave >> 1) == ph) {
#pragma unroll
      for (int i = 0; i < 4; i++)
#pragma unroll
        for (int j = 0; j < 4; j++)
#pragma unroll
          for (int r = 0; r < 4; r++)
            cb[(i * 16 + lg * 4 + r) * 136 + wn + j * 16 + l15] =
                (_Float16)acc[i][j][r];
    }
    __syncthreads();
    if (MODE == 0) {
#pragma unroll
      for (int rr = 0; rr < 4; rr++) {
        int row = rr * 16 + (tid >> 4);   // 0..63
        int colh = (tid & 15) * 8;        // 16 lanes cover 256B contiguous
        uint4 v = *(const uint4*)&cb[row * 136 + colh];
        *(uint4*)&C[(size_t)(bm0 + ph * 64 + row) * N + bn0 + colh] = v;
      }
    } else if (MODE == 2) {
      // K fragment pack: tile cols = [K(512)|K2(512)], bx<4 -> K (ks 0,1), else K2 (ks 2,3)
      int m0 = bm0 + ph * 64;
      int b = m0 >> 10;
      int kblk0 = (m0 & 1023) >> 4;
      int isK2 = (bn0 >= 512) ? 1 : 0;
      int hpair = (isK2 ? (bx - 4) : bx) * 2;
      int sel = tid >> 6;          // 0..3
      int hh = sel >> 1, ksl = sel & 1;
      int bh = b * 8 + hpair + hh;
      int ksd = isK2 * 2 + ksl;
#pragma unroll
      for (int kb = 0; kb < 4; kb++) {
        f16x8 v = *(const f16x8*)&cb[(kb * 16 + l15) * 136 + hh * 64 + ksl * 32 + lg * 8];
        *(f16x8*)(pk + ((((size_t)bh * 64 + kblk0 + kb) * 4 + ksd) * 64 + lane) * 8) = v;
      }
    } else if (MODE == 1) {
      // V fragment pack: lane's 8 halves = 8 consecutive KEYS for fixed dv (LDS transpose)
      int m0 = bm0 + ph * 64;
      int b = m0 >> 10;
      int k320 = (m0 & 1023) >> 5;
      int sel = tid >> 6;
      int hh = sel >> 1, kk2 = sel & 1;
      int bh = b * 8 + bx * 2 + hh;
#pragma unroll
      for (int dvb = 0; dvb < 4; dvb++) {
        f16x8 v;
#pragma unroll
        for (int j = 0; j < 8; j++)
          v[j] = cb[(kk2 * 32 + lg * 8 + j) * 136 + hh * 64 + dvb * 16 + l15];
        *(f16x8*)(pk + ((((size_t)bh * 32 + k320 + kk2) * 4 + dvb) * 64 + lane) * 8) = v;
      }
    } else {
      // Q fragment pack: Qpk[bqt][h][mi][ks][lane][8]; cols [Q(512)|Q2(512)]
      int m0 = bm0 + ph * 64;
      int b = m0 >> 10;
      int qt0 = (m0 & 1023) >> 5;  // first of 2 qt in this 64-row pass
      int isQ2 = (bn0 >= 512) ? 1 : 0;
      int h0 = ((isQ2 ? (bn0 - 512) : bn0) >> 6);
      int sel = tid >> 6;
      int hh = sel >> 1, qth = sel & 1;
      int bqt = b * 32 + qt0 + qth;
      int h = h0 + hh;
#pragma unroll
      for (int mi = 0; mi < 2; mi++)
#pragma unroll
        for (int ksl = 0; ksl < 2; ksl++) {
          f16x8 v = *(const f16x8*)&cb[(qth * 32 + mi * 16 + l15) * 136 + hh * 64 +
                                       ksl * 32 + lg * 8];
          int ks = isQ2 * 2 + ksl;
          *(f16x8*)(pk + ((((size_t)bqt * 8 + h) * 2 + mi) * 4 + ks) * 512 +
                    lane * 8) = v;
        }
    }
  }
}

// fused Q/K/V projections + fragment packing + mask pack (z selects)
__global__ __launch_bounds__(256) void proj_kernel(
    const float* __restrict__ inQ, const float* __restrict__ inK,
    const float* __restrict__ inV, const __half* __restrict__ WqcT,
    const __half* __restrict__ WkcT, const __half* __restrict__ WvT,
    const int* __restrict__ am, const int* __restrict__ bm,
    __half* __restrict__ Qpk, __half* __restrict__ Kpk, __half* __restrict__ Vpk,
    uint32_t* __restrict__ packed) {
  int z = blockIdx.z;
  if (z == 0) {
    gemm_body<1, 3>(inQ, WqcT, nullptr, 1024, blockIdx.x, blockIdx.y, Qpk);
  } else if (z == 1) {
    gemm_body<1, 2>(inK, WkcT, nullptr, 1024, blockIdx.x, blockIdx.y, Kpk);
  } else if (z == 2) {
    if (blockIdx.x >= 4) return;
    gemm_body<1, 1>(inV, WvT, nullptr, 512, blockIdx.x, blockIdx.y, Vpk);
  } else {
    // mask pack: 256 blocks x 256 threads cover bk 0..511 (2 per block)
    int bk = (blockIdx.y * 8 + blockIdx.x) * 2 + (threadIdx.x >> 7);
    maskprep_body(am, bm, packed, bk, threadIdx.x & 127);
  }
}

__global__ __launch_bounds__(256) void gemm_f16_kernel(const __half* __restrict__ A,
                                                       const __half* __restrict__ Bt,
                                                       __half* __restrict__ C, int N) {
  gemm_body<0, 0>(A, Bt, C, N, blockIdx.x, blockIdx.y, nullptr);
}

// ---------- fused attention (round-11 configuration + Qpk loads) ----------
// INVARIANTS (round-7 isolation): 2D grid (qt,bh), no swizzle; attn global writes
// from registers, scalar f32 (no nt — round-15), ONE phase before PV; 67.6 KB
// LDS -> 2 blocks/CU; ALL of Q/K/V loaded from fragment-packed coalesced layouts.
__global__ __launch_bounds__(256, 2) void attn_kernel(
    const __half* __restrict__ Qpk, const __half* __restrict__ Kpk,
    const __half* __restrict__ Vpk, const uint32_t* __restrict__ packed,
    float* __restrict__ attn_out, __half* __restrict__ CTX) {
  int qt = blockIdx.x, bh = blockIdx.y;
  int b = bh >> 3, h = bh & 7;
  int q0 = qt * 32;
  int tid = threadIdx.x;
  int wave = tid >> 6, lane = tid & 63;
  int lg = lane >> 4, l15 = lane & 15;
  int kw = wave * 256;

  __shared__ __align__(16) _Float16 P[4][32][264];  // 67.6 KB -> 2 blocks/CU
  __shared__ float redmax[4][32], redsum[4][32];

  // ---- Q fragments from Qpk (coalesced 1KB wave-loads) ----
  f16x8 qf[2][4];
  const __half* Qbp =
      Qpk + (((size_t)(b * 32 + qt) * 8 + h) * 8) * 512 + lane * 8;
#pragma unroll
  for (int mi = 0; mi < 2; mi++)
#pragma unroll
    for (int ks = 0; ks < 4; ks++)
      qf[mi][ks] = *(const f16x8*)(Qbp + (size_t)(mi * 4 + ks) * 512);

  // ---- packed mask words ----
  uint4 mw[2];
  {
    const uint4* mp =
        (const uint4*)packed + ((size_t)((b * 32 + qt) * 4 + wave) * 64 + lane) * 2;
    mw[0] = mp[0];
    mw[1] = mp[1];
  }

  // ---- phase 1: scores -> f16 regs, track max (coalesced Kpk loads) ----
  f16x4 sc16[2][16];
  float mx[2][4];
#pragma unroll
  for (int mi = 0; mi < 2; mi++)
#pragma unroll
    for (int r = 0; r < 4; r++) mx[mi][r] = -3.0e38f;
  const __half* Kbp = Kpk + ((size_t)bh * 64 + wave * 16) * 4 * 512 + lane * 8;
#pragma unroll
  for (int kt = 0; kt < 16; kt++) {
    const __half* kp = Kbp + (size_t)kt * 4 * 512;
    f16x8 kf[4];
    kf[0] = *(const f16x8*)kp;
    kf[1] = *(const f16x8*)(kp + 512);
    kf[2] = *(const f16x8*)(kp + 1024);
    kf[3] = *(const f16x8*)(kp + 1536);
#pragma unroll
    for (int mi = 0; mi < 2; mi++) {
      f32x4 s = (f32x4){0.f, 0.f, 0.f, 0.f};
#pragma unroll
      for (int ks = 0; ks < 4; ks++)
        s = __builtin_amdgcn_mfma_f32_16x16x32_f16(qf[mi][ks], kf[ks], s, 0, 0, 0);
      uint32_t mword = ((const uint32_t*)&mw[mi])[kt >> 2];
      f16x4 sv;
#pragma unroll
      for (int r = 0; r < 4; r++) {
        uint32_t code = (mword >> (((kt & 3) << 3) + (r << 1))) & 3u;
        float sval = s[r] - 30000.0f * (float)code;
        sv[r] = (_Float16)sval;
        mx[mi][r] = fmaxf(mx[mi][r], (float)sv[r]);
      }
      sc16[mi][kt] = sv;
    }
  }

  // ---- max reduce ----
#pragma unroll
  for (int mi = 0; mi < 2; mi++)
#pragma unroll
    for (int r = 0; r < 4; r++) {
      float m = mx[mi][r];
#pragma unroll
      for (int o = 1; o < 16; o <<= 1) m = fmaxf(m, __shfl_xor(m, o));
      if (l15 == 0) redmax[wave][mi * 16 + lg * 4 + r] = m;
    }
  __syncthreads();
  float mfin[2][4];
#pragma unroll
  for (int mi = 0; mi < 2; mi++)
#pragma unroll
    for (int r = 0; r < 4; r++) {
      int row = mi * 16 + lg * 4 + r;
      mfin[mi][r] = fmaxf(fmaxf(redmax[0][row], redmax[1][row]),
                          fmaxf(redmax[2][row], redmax[3][row]));
    }

  // ---- p = exp(s-m) in f16 regs, sum reduce ----
  float sm[2][4];
#pragma unroll
  for (int mi = 0; mi < 2; mi++)
#pragma unroll
    for (int r = 0; r < 4; r++) sm[mi][r] = 0.f;
#pragma unroll
  for (int kt = 0; kt < 16; kt++)
#pragma unroll
    for (int mi = 0; mi < 2; mi++) {
      f16x4 sv = sc16[mi][kt];
      f16x4 pv;
#pragma unroll
      for (int r = 0; r < 4; r++) {
        float p = __expf((float)sv[r] - mfin[mi][r]);
        sm[mi][r] += p;
        pv[r] = (_Float16)p;
      }
      sc16[mi][kt] = pv;
    }
#pragma unroll
  for (int mi = 0; mi < 2; mi++)
#pragma unroll
    for (int r = 0; r < 4; r++) {
      float s = sm[mi][r];
#pragma unroll
      for (int o = 1; o < 16; o <<= 1) s += __shfl_xor(s, o);
      if (l15 == 0) redsum[wave][mi * 16 + lg * 4 + r] = s;
    }
  __syncthreads();
  float inv[2][4];
#pragma unroll
  for (int mi = 0; mi < 2; mi++)
#pragma unroll
    for (int r = 0; r < 4; r++) {
      int row = mi * 16 + lg * 4 + r;
      inv[mi][r] =
          1.0f / (redsum[0][row] + redsum[1][row] + redsum[2][row] + redsum[3][row]);
    }

  // ---- write phase: attn strip from regs (plain scalar f32) + stage P[wave] ----
  float* ab = attn_out + ((size_t)bh * 1024 + q0) * 1024;
#pragma unroll
  for (int mi = 0; mi < 2; mi++)
#pragma unroll
    for (int kt = 0; kt < 16; kt++)
#pragma unroll
      for (int r = 0; r < 4; r++) {
        int row = mi * 16 + lg * 4 + r;
        int col = kw + kt * 16 + l15;
        float a = (float)sc16[mi][kt][r] * inv[mi][r];
        ab[(size_t)row * 1024 + col] = a;
        P[wave][row][kt * 16 + l15] = (_Float16)a;
      }
  __syncthreads();

  // ---- PV over 4 chunks, no further barriers; wave owns dv slice [16w,16w+16) ----
  f32x4 ctx[2];
  ctx[0] = (f32x4){0.f, 0.f, 0.f, 0.f};
  ctx[1] = (f32x4){0.f, 0.f, 0.f, 0.f};
  const __half* Vbp = Vpk + ((size_t)bh * 32 * 4 + wave) * 512 + lane * 8;
#pragma unroll
  for (int c = 0; c < 4; c++) {
#pragma unroll
    for (int kk = 0; kk < 8; kk++) {
      int k32 = c * 8 + kk;
      f16x8 pa0 = *(const f16x8*)&P[c][l15][kk * 32 + lg * 8];
      f16x8 pa1 = *(const f16x8*)&P[c][16 + l15][kk * 32 + lg * 8];
      f16x8 vf = *(const f16x8*)(Vbp + (size_t)k32 * 4 * 512);
      ctx[0] = __builtin_amdgcn_mfma_f32_16x16x32_f16(pa0, vf, ctx[0], 0, 0, 0);
      ctx[1] = __builtin_amdgcn_mfma_f32_16x16x32_f16(pa1, vf, ctx[1], 0, 0, 0);
    }
  }

  // ---- ctx write: wave owns dv slice [16w,16w+16) ----
#pragma unroll
  for (int mi = 0; mi < 2; mi++)
#pragma unroll
    for (int r = 0; r < 4; r++) {
      int row = mi * 16 + lg * 4 + r;
      CTX[(size_t)(b * 1024 + q0 + row) * 512 + h * 64 + wave * 16 + l15] =
          __float2half(ctx[mi][r]);
    }
}

// ---------- residual + LayerNorm: wave-per-row, no LDS, no barriers ----------
__global__ __launch_bounds__(256) void ln_kernel(const __half* __restrict__ O,
                                                 const float* __restrict__ resid,
                                                 const float* __restrict__ g,
                                                 const float* __restrict__ bb,
                                                 float* __restrict__ out) {
  int w = threadIdx.x >> 6, lane = threadIdx.x & 63;
  int row = blockIdx.x * 4 + w;
  size_t base = (size_t)row * 512 + lane * 8;
  f16x8 ov = *(const f16x8*)(O + base);
  float4 r0 = *(const float4*)(resid + base);
  float4 r1 = *(const float4*)(resid + base + 4);
  float x[8];
  x[0] = (float)ov[0] + r0.x; x[1] = (float)ov[1] + r0.y;
  x[2] = (float)ov[2] + r0.z; x[3] = (float)ov[3] + r0.w;
  x[4] = (float)ov[4] + r1.x; x[5] = (float)ov[5] + r1.y;
  x[6] = (float)ov[6] + r1.z; x[7] = (float)ov[7] + r1.w;
  float s = 0.f;
#pragma unroll
  for (int i = 0; i < 8; i++) s += x[i];
#pragma unroll
  for (int o = 1; o < 64; o <<= 1) s += __shfl_xor(s, o);
  float mean = s * (1.0f / 512.0f);
  float d[8], v = 0.f;
#pragma unroll
  for (int i = 0; i < 8; i++) { d[i] = x[i] - mean; v += d[i] * d[i]; }
#pragma unroll
  for (int o = 1; o < 64; o <<= 1) v += __shfl_xor(v, o);
  float rs = rsqrtf(v * (1.0f / 512.0f) + 1e-5f);
  float4 g0 = *(const float4*)(g + lane * 8);
  float4 g1 = *(const float4*)(g + lane * 8 + 4);
  float4 b0 = *(const float4*)(bb + lane * 8);
  float4 b1 = *(const float4*)(bb + lane * 8 + 4);
  f32x4 o0 = {d[0] * rs * g0.x + b0.x, d[1] * rs * g0.y + b0.y,
              d[2] * rs * g0.z + b0.z, d[3] * rs * g0.w + b0.w};
  f32x4 o1 = {d[4] * rs * g1.x + b1.x, d[5] * rs * g1.y + b1.y,
              d[6] * rs * g1.z + b1.z, d[7] * rs * g1.w + b1.w};
  __builtin_nontemporal_store(o0, (f32x4*)(out + base));
  __builtin_nontemporal_store(o1, (f32x4*)(out + base + 4));
}

extern "C" void kernel_launch(void* const* d_in, const int* in_sizes, int n_in,
                              void* d_out, int out_size, void* d_ws, size_t ws_size,
                              hipStream_t stream) {
  const float* inQ = (const float*)d_in[0];
  const float* inK = (const float*)d_in[1];
  const float* inV = (const float*)d_in[2];
  const int* am = (const int*)d_in[3];
  const int* bmk = (const int*)d_in[4];
  const float* Wq = (const float*)d_in[5];
  const float* Wk = (const float*)d_in[6];
  const float* Wq2 = (const float*)d_in[7];
  const float* Wk2 = (const float*)d_in[8];
  const float* Wv = (const float*)d_in[9];
  const float* Wo = (const float*)d_in[10];
  const float* lng = (const float*)d_in[11];
  const float* lnb = (const float*)d_in[12];

  char* ws = (char*)d_ws;
  __half* WqcT = (__half*)ws; ws += (size_t)1024 * 512 * 2;
  __half* WkcT = (__half*)ws; ws += (size_t)1024 * 512 * 2;
  __half* WvT = (__half*)ws;  ws += (size_t)512 * 512 * 2;
  __half* WoT = (__half*)ws;  ws += (size_t)512 * 512 * 2;
  __half* Qpk = (__half*)ws;  ws += (size_t)4096 * 1024 * 2;
  __half* Kpk = (__half*)ws;  ws += (size_t)4096 * 1024 * 2;
  __half* Vpk = (__half*)ws;  ws += (size_t)4096 * 512 * 2;
  __half* CTX = (__half*)ws;  ws += (size_t)4096 * 512 * 2;
  __half* Obuf = (__half*)ws; ws += (size_t)4096 * 512 * 2;
  uint32_t* packed = (uint32_t*)Obuf;  // alias: packed dead before Obuf written

  float* out0 = (float*)d_out;
  float* attn_out = out0 + (size_t)4 * 1024 * 512;

  wtrans6_kernel<<<dim3(16, 16, 6), dim3(32, 8), 0, stream>>>(Wq, Wk, Wq2, Wk2, Wv, Wo,
                                                              WqcT, WkcT, WvT, WoT);
  proj_kernel<<<dim3(8, 32, 4), 256, 0, stream>>>(inQ, inK, inV, WqcT, WkcT, WvT, am,
                                                  bmk, Qpk, Kpk, Vpk, packed);
  attn_kernel<<<dim3(32, 32), 256, 0, stream>>>(Qpk, Kpk, Vpk, packed, attn_out, CTX);
  gemm_f16_kernel<<<dim3(4, 32), 256, 0, stream>>>(CTX, WoT, Obuf, 512);
  ln_kernel<<<1024, 256, 0, stream>>>(Obuf, inQ, lng, lnb, out0);
}